// Round 3
// baseline (33141.464 us; speedup 1.0000x reference)
//
#include <hip/hip_runtime.h>
#include <stdint.h>

typedef __attribute__((ext_vector_type(8))) short short8;
typedef __attribute__((ext_vector_type(8))) _Float16 half8;
typedef __attribute__((ext_vector_type(4))) float f32x4;

// ---------- sizes ----------
#define NS 512
// ws element offsets (fp16/ushort units)
#define O_PW  0L           // [256 blk][12 row][2048 k] fp16 = 6,291,456
#define O_X   6291456L     // [512 s][128 b][1024 k] fp16 = 67,108,864
#define O_HB  73400320L    // [2][128][1024] fp16 ping-pong = 262,144
#define O_CNT 73662464L    // uint32 cnt[512] (byte offset 147,324,928)

// LDS layout (bytes), dynamic:
//   lds_w  : 12 rows x 2056 fp16 (padded)        = 49,344
//   A-bufs : 8 waves x 2 bufs x 4096             = 65,536   (at 49,344)
//   xch    : 8 mtiles x 64 lanes x 16 B          =  8,192   (at 114,880)
//   sflag  : int                                  (at 123,072)
#define LDS_BYTES 123088

// ---------- prep: pack weights per block as fp16 [blk][row<12][k<2048] ----------
// row: 0-3 = z cols j0..j0+3, 4-7 = r, 8-11 = n; k<1024 -> W_ih, else W_hh
__global__ void prep_w(const float* __restrict__ Wih, const float* __restrict__ Whh,
                       _Float16* __restrict__ pw)
{
    long i = (long)blockIdx.x * 256 + threadIdx.x;   // 6,291,456 total
    if (i >= 6291456L) return;
    int k = (int)(i & 2047);
    long t = i >> 11;
    int row = (int)(t % 12);
    int blk = (int)(t / 12);
    int g = row >> 2;
    int jj = (blk << 2) + (row & 3);
    float w = (k < 1024) ? Wih[((long)((g << 10) + jj) << 10) + k]
                         : Whh[((long)((g << 10) + jj) << 10) + (k - 1024)];
    pw[i] = (_Float16)w;
}

// ---------- prep: x (B,S,I) f32 -> (S,B,I) fp16 ----------
__global__ void prep_x(const float* __restrict__ x, _Float16* __restrict__ xh)
{
    long t = (long)blockIdx.x * 256 + threadIdx.x;
    long base = t * 8;
    if (base >= 67108864L) return;
    long b = base >> 19;
    long rem = base & 524287L;
    long s = rem >> 10;
    long k = rem & 1023L;
    const float4* xp = (const float4*)(x + base);
    float4 v0 = xp[0], v1 = xp[1];
    half8 sv;
    sv[0] = (_Float16)v0.x; sv[1] = (_Float16)v0.y;
    sv[2] = (_Float16)v0.z; sv[3] = (_Float16)v0.w;
    sv[4] = (_Float16)v1.x; sv[5] = (_Float16)v1.y;
    sv[6] = (_Float16)v1.z; sv[7] = (_Float16)v1.w;
    *(half8*)(xh + ((s * 128 + b) << 10) + k) = sv;
}

// ---------- prep: h0 -> hb[0] fp16, hn output tail, zero barrier counters ----------
__global__ void prep_h(const float* __restrict__ h0, _Float16* __restrict__ hb,
                       float* __restrict__ outTail, unsigned int* __restrict__ cnt)
{
    int i = blockIdx.x * 256 + threadIdx.x;          // 131072
    float v = h0[i];
    hb[i] = (_Float16)v;
    outTail[i] = v;
    if (i < 512) cnt[i] = 0u;
}

// ---------- persistent GRU recurrence ----------
// grid 256 (1/CU) x 4 h-cols; 512 thr = 8 waves.
// waves 0-3: x-half of K (m-tiles 2w,2w+1); waves 4-7: h-half (same m-tiles).
// Weights LDS-resident (staged once). A staged per-wave via global_load_lds,
// double-buffered 4KB chunks, counted vmcnt. Grid barrier via cnt[s] atomics.
__global__ __launch_bounds__(512) void gru_persist(
    const _Float16* __restrict__ xh, const _Float16* __restrict__ pw,
    _Float16* __restrict__ hb, unsigned int* __restrict__ cnt,
    const float* __restrict__ bias, const float* __restrict__ h0,
    float* __restrict__ out)
{
    extern __shared__ char smem[];
    _Float16* lds_w = (_Float16*)smem;
    char*     abase = smem + 49344;
    f32x4*    xch   = (f32x4*)(smem + 114880);
    volatile int* sflag = (volatile int*)(smem + 123072);

    const int tid  = threadIdx.x;
    const int wave = tid >> 6, lane = tid & 63;
    const int half = wave >> 2, w4 = wave & 3;
    const int row  = lane & 15, kg = lane >> 4;
    const int j0   = blockIdx.x << 2;

    // ---- stage weights once: pw[blk] (24576 fp16) -> padded LDS rows ----
    {
        const _Float16* src = pw + (long)blockIdx.x * 24576;
        #pragma unroll
        for (int it = 0; it < 6; ++it) {
            int e = (it * 512 + tid) << 3;
            int r = e >> 11, k = e & 2047;
            *(half8*)&lds_w[r * 2056 + k] = *(const half8*)(src + e);
        }
    }
    if (tid == 0) *sflag = -1;
    __syncthreads();

    const int myrl = (row < 12) ? row : (row - 8);   // lanes 12-15: broadcast dup
    char* bufA = abase + wave * 8192;
    char* bufB = bufA + 4096;

    // per-lane global gather offsets for staging (inverse-swizzled source)
    int rowoff[4];
    #pragma unroll
    for (int ii = 0; ii < 4; ++ii)
        rowoff[ii] = ((w4 << 5) + (ii << 3) + (lane >> 3)) * 1024
                   + (((lane & 7) ^ (lane >> 3)) << 3);

    // f32 master h lives in registers of the epilogue lanes
    float hreg[2][4];
    #pragma unroll
    for (int mi = 0; mi < 2; ++mi)
        #pragma unroll
        for (int i = 0; i < 4; ++i) {
            int b = (w4 << 5) + (mi << 4) + (kg << 2) + i;
            hreg[mi][i] = (!half && row < 4) ? h0[((long)b << 10) + j0 + row] : 0.f;
        }

    const float bz = bias[j0 + (row & 3)];
    const float br = bias[1024 + j0 + (row & 3)];
    const float bn = bias[2048 + j0 + (row & 3)];

    #define ISSUE(c, bufp) { \
        const _Float16* g0 = Ag + ((c) << 6); \
        _Pragma("unroll") \
        for (int ii = 0; ii < 4; ++ii) { \
            __builtin_amdgcn_global_load_lds( \
                (const __attribute__((address_space(1))) unsigned int*)(g0 + rowoff[ii]), \
                (__attribute__((address_space(3))) unsigned int*)((bufp) + ii * 1024 + lane * 16), \
                16, 0, 0); \
        } }

    #define COMPUTE_CHUNK(bc, c) { \
        _Pragma("unroll") \
        for (int ktl = 0; ktl < 2; ++ktl) { \
            half8 fb = *(const half8*)&lds_w[myrl * 2056 + (half << 10) + ((c) * 2 + ktl) * 32 + (kg << 3)]; \
            half8 fa0 = *(const half8*)((bc) + row * 128 + ((((ktl << 2) + kg) ^ (row & 7)) << 4)); \
            half8 fa1 = *(const half8*)((bc) + (16 + row) * 128 + ((((ktl << 2) + kg) ^ (row & 7)) << 4)); \
            acc0 = __builtin_amdgcn_mfma_f32_16x16x32_f16(fa0, fb, acc0, 0, 0, 0); \
            acc1 = __builtin_amdgcn_mfma_f32_16x16x32_f16(fa1, fb, acc1, 0, 0, 0); \
        } }

    for (int s = 0; s < NS; ++s) {
        const _Float16* Ag = half ? (hb + ((long)(s & 1) << 17))
                                  : (xh + ((long)s << 17));
        if (half && s > 0) {
            // one global poller per block; others spin on LDS flag
            if (wave == 4 && lane == 0) {
                unsigned int v;
                do {
                    __builtin_amdgcn_s_sleep(1);
                    v = __hip_atomic_load(&cnt[s - 1], __ATOMIC_ACQUIRE, __HIP_MEMORY_SCOPE_AGENT);
                } while (v < 256u);
                *sflag = s;
            }
            while (*sflag < s) { __builtin_amdgcn_s_sleep(1); }
            asm volatile("" ::: "memory");
            __builtin_amdgcn_sched_barrier(0);
        }

        f32x4 acc0 = {0,0,0,0}, acc1 = {0,0,0,0};
        ISSUE(0, bufA);
        ISSUE(1, bufB);
        for (int c = 0; c < 15; ++c) {
            asm volatile("s_waitcnt vmcnt(4)" ::: "memory");
            __builtin_amdgcn_sched_barrier(0);
            char* bc = (c & 1) ? bufB : bufA;
            COMPUTE_CHUNK(bc, c);
            asm volatile("s_waitcnt lgkmcnt(0)" ::: "memory");
            __builtin_amdgcn_sched_barrier(0);
            if (c < 14) { ISSUE(c + 2, bc); }
        }
        asm volatile("s_waitcnt vmcnt(0)" ::: "memory");
        __builtin_amdgcn_sched_barrier(0);
        COMPUTE_CHUNK(bufB, 15);

        // ---- combine halves + gates + h update ----
        __syncthreads();
        if (half) {
            xch[((w4 << 1) + 0) * 64 + lane] = acc0;
            xch[((w4 << 1) + 1) * 64 + lane] = acc1;
        }
        __syncthreads();
        if (!half) {
            const int c = row;
            _Float16* hw = hb + ((long)((s + 1) & 1) << 17);
            #pragma unroll
            for (int mi = 0; mi < 2; ++mi) {
                f32x4 sx = mi ? acc1 : acc0;
                f32x4 sh = xch[((w4 << 1) + mi) * 64 + lane];
                #pragma unroll
                for (int i = 0; i < 4; ++i) {
                    float sxv = sx[i], shv = sh[i];
                    float vx4 = __shfl(sxv, lane + 4);
                    float vh4 = __shfl(shv, lane + 4);
                    float vx8 = __shfl(sxv, lane + 8);
                    float vh8 = __shfl(shv, lane + 8);
                    if (c < 4) {
                        int b = (w4 << 5) + (mi << 4) + (kg << 2) + i;
                        int j = j0 + c;
                        float z = 1.f / (1.f + __expf(-(sxv + shv + bz)));
                        float r = 1.f / (1.f + __expf(-(vx4 + vh4 + br)));
                        float inner = vx8 + bn + vh8 + r * (vh8 + bn);
                        float e2 = __expf(2.f * inner);
                        float n = 1.f - 2.f / (e2 + 1.f);     // tanh(inner)
                        float hv = (1.f - z) * n + z * hreg[mi][i];
                        hreg[mi][i] = hv;
                        hw[((long)b << 10) + j] = (_Float16)hv;
                        out[((long)b << 19) + ((long)s << 10) + j] = hv;
                    }
                }
            }
        }
        __threadfence();
        __syncthreads();
        if (tid == 0)
            __hip_atomic_fetch_add(&cnt[s], 1u, __ATOMIC_RELEASE, __HIP_MEMORY_SCOPE_AGENT);
    }
}

extern "C" void kernel_launch(void* const* d_in, const int* in_sizes, int n_in,
                              void* d_out, int out_size, void* d_ws, size_t ws_size,
                              hipStream_t stream)
{
    const float* x    = (const float*)d_in[0];
    const float* Wih  = (const float*)d_in[1];
    const float* Whh  = (const float*)d_in[2];
    const float* bias = (const float*)d_in[3];
    const float* h0   = (const float*)d_in[4];
    float* out = (float*)d_out;

    _Float16* ws16 = (_Float16*)d_ws;
    _Float16* pw = ws16 + O_PW;
    _Float16* xh = ws16 + O_X;
    _Float16* hb = ws16 + O_HB;
    unsigned int* cnt = (unsigned int*)(ws16 + O_CNT);

    (void)hipFuncSetAttribute((const void*)gru_persist,
                              hipFuncAttributeMaxDynamicSharedMemorySize, LDS_BYTES);

    prep_w<<<24576, 256, 0, stream>>>(Wih, Whh, pw);
    prep_x<<<32768, 256, 0, stream>>>(x, xh);
    prep_h<<<512, 256, 0, stream>>>(h0, hb, out + 67108864L, cnt);

    gru_persist<<<256, 512, LDS_BYTES, stream>>>(xh, pw, hb, cnt, bias, h0, out);
}

// Round 4
// 7506.980 us; speedup vs baseline: 4.4148x; 4.4148x over previous
//
#include <hip/hip_runtime.h>
#include <stdint.h>

typedef __attribute__((ext_vector_type(8))) _Float16 half8;
typedef __attribute__((ext_vector_type(4))) float f32x4;

// ---------- ws element offsets (fp16 units) ----------
#define O_PW  0L           // [128 jg][4 kq][16 kb][768] fp16 = 6,291,456 (fragment-major)
#define O_X   6291456L     // [512 s][128 b][1024 k] fp16 = 67,108,864
#define O_HB  73400320L    // [2][128][1024] fp16 ping-pong = 262,144
#define O_HF  73662464L    // 131072 f32 master h (= 262,144 fp16 slots)

// LDS: B fragments 98,304 B + xch 24,576 B
#define LDS_BYTES 122880

// ---------- prep: pack weights fragment-major fp16 ----------
// Per jg (8 output cols): 4 K-quarters (kq 0-1 = W_ih, 2-3 = W_hh) x 16 kb (32 k each).
// Per (kq,kb) 1536 B: T0 = 64 slots x 16 B (slot=lane: col=slot&15 -> z j0+c (c<8) | r j0+c-8; kg=slot>>4),
//                     T1 = 32 slots x 16 B (idx: row7=idx&7 -> n j0+row7; kg=idx>>3).
__global__ void prep_w(const float* __restrict__ Wih, const float* __restrict__ Whh,
                       _Float16* __restrict__ pw)
{
    long i = (long)blockIdx.x * 256 + threadIdx.x;   // 6,291,456 total
    if (i >= 6291456L) return;
    int jg = (int)(i / 49152);
    int r  = (int)(i % 49152);
    int kq = r / 12288;  r %= 12288;
    int kb = r / 768;    r %= 768;
    int slot = r >> 3, e = r & 7;
    int wrow, kg;
    if (slot < 64) {                 // T0: z | r
        int c = slot & 15; kg = slot >> 4;
        wrow = (c < 8) ? (jg * 8 + c) : (1024 + jg * 8 + (c - 8));
    } else {                         // T1: n (row/row+8 dup at read)
        int idx = slot - 64; kg = idx >> 3;
        wrow = 2048 + jg * 8 + (idx & 7);
    }
    int klocal = (kq & 1) * 512 + kb * 32 + kg * 8 + e;
    const float* src = (kq >> 1) ? Whh : Wih;
    pw[i] = (_Float16)src[(long)wrow * 1024 + klocal];
}

// ---------- prep: x (B,S,I) f32 -> (S,B,I) fp16 ----------
__global__ void prep_x(const float* __restrict__ x, _Float16* __restrict__ xh)
{
    long t = (long)blockIdx.x * 256 + threadIdx.x;
    long base = t * 8;
    if (base >= 67108864L) return;
    long b = base >> 19;
    long rem = base & 524287L;
    long s = rem >> 10;
    long k = rem & 1023L;
    const float4* xp = (const float4*)(x + base);
    float4 v0 = xp[0], v1 = xp[1];
    half8 sv;
    sv[0] = (_Float16)v0.x; sv[1] = (_Float16)v0.y;
    sv[2] = (_Float16)v0.z; sv[3] = (_Float16)v0.w;
    sv[4] = (_Float16)v1.x; sv[5] = (_Float16)v1.y;
    sv[6] = (_Float16)v1.z; sv[7] = (_Float16)v1.w;
    *(half8*)(xh + ((s * 128 + b) << 10) + k) = sv;
}

// ---------- prep: h0 -> hb[0] fp16, hf f32, hn output tail ----------
__global__ void prep_h(const float* __restrict__ h0, _Float16* __restrict__ hb,
                       float* __restrict__ hf, float* __restrict__ outTail)
{
    int i = blockIdx.x * 256 + threadIdx.x;          // 131072
    float v = h0[i];
    hb[i] = (_Float16)v;
    hf[i] = v;
    outTail[i] = v;
}

// ---------- one GRU step ----------
// grid 256 = 128 jg (8 out cols) x 2 mg (64 batches); 512 thr = 8 waves.
// wave: mt2 = wave&1 (32-batch subtile), kq = wave>>1 (512-k quarter; 0-1 x, 2-3 h).
// B: LDS fragment-major (staged via linear global_load_lds). A: direct global->VGPR.
__global__ __launch_bounds__(512) void gru_step(
    const _Float16* __restrict__ xh, const _Float16* __restrict__ pw,
    _Float16* __restrict__ hb, float* __restrict__ hf,
    const float* __restrict__ bias, float* __restrict__ out, int s)
{
    extern __shared__ char smem[];

    const int tid  = threadIdx.x;
    const int wave = tid >> 6, lane = tid & 63;
    const int mt2  = wave & 1, kq = wave >> 1;
    const int kh   = kq >> 1;                  // 0 = x half, 1 = h half
    const int ksrc = (kq & 1) * 512;           // k offset within 1024-wide source
    const int row  = lane & 15, kg = lane >> 4;
    const int jg   = blockIdx.x >> 1, mg = blockIdx.x & 1;
    const int j0   = jg << 3, mgbase = mg << 6;
    const int t1x  = (lane & 7) | ((lane >> 4) << 3);

    // ---- A fragment pointers + prologue prefetch (depth 4) ----
    const _Float16* Asrc = kh ? (hb + ((long)(s & 1) << 17)) : (xh + ((long)s << 17));
    const _Float16* a0p = Asrc + (long)(mgbase + mt2 * 32 + row) * 1024 + ksrc + kg * 8;
    const _Float16* a1p = a0p + 16 * 1024;
    half8 qa0[4], qa1[4];
    #pragma unroll
    for (int p = 0; p < 4; ++p) { qa0[p] = *(const half8*)(a0p + p * 32);
                                  qa1[p] = *(const half8*)(a1p + p * 32); }

    // ---- stage B fragments: 98,304 B linear via global_load_lds ----
    {
        const char* src = (const char*)(pw + (long)jg * 49152);
        #pragma unroll
        for (int it = 0; it < 12; ++it) {
            int off = it * 8192 + tid * 16;
            __builtin_amdgcn_global_load_lds(
                (const __attribute__((address_space(1))) unsigned int*)(src + off),
                (__attribute__((address_space(3))) unsigned int*)(smem + off), 16, 0, 0);
        }
    }
    asm volatile("s_waitcnt vmcnt(0)" ::: "memory");
    __syncthreads();

    // ---- main loop: 16 kb, 4 MFMAs each, depth-4 A prefetch (static idx) ----
    f32x4 acc00 = {0,0,0,0}, acc01 = {0,0,0,0};    // T0(z|r) x a0,a1
    f32x4 acc10 = {0,0,0,0}, acc11 = {0,0,0,0};    // T1(n)   x a0,a1
    const char* Bbase = smem + kq * 24576;
    #define MFMA(a,b,c) __builtin_amdgcn_mfma_f32_16x16x32_f16((a),(b),(c),0,0,0)
    #pragma unroll
    for (int kb = 0; kb < 16; ++kb) {
        half8 fa0 = qa0[kb & 3], fa1 = qa1[kb & 3];
        half8 fb0 = *(const half8*)(Bbase + kb * 1536 + lane * 16);
        half8 fb1 = *(const half8*)(Bbase + kb * 1536 + 1024 + t1x * 16);
        acc00 = MFMA(fa0, fb0, acc00);
        acc01 = MFMA(fa1, fb0, acc01);
        acc10 = MFMA(fa0, fb1, acc10);
        acc11 = MFMA(fa1, fb1, acc11);
        if (kb < 12) { qa0[kb & 3] = *(const half8*)(a0p + (kb + 4) * 32);
                       qa1[kb & 3] = *(const half8*)(a1p + (kb + 4) * 32); }
    }

    // ---- exchange partials across K-quarters ----
    f32x4* xch = (f32x4*)(smem + 98304);
    if (kq) {
        int base = ((mt2 * 3 + (kq - 1)) * 4) * 64 + lane;
        xch[base]       = acc00;
        xch[base + 64]  = acc01;
        xch[base + 128] = acc10;
        xch[base + 192] = acc11;
    }
    __syncthreads();

    if (kq == 0) {
        #define XC(q,a) xch[((mt2 * 3 + (q)) * 4 + (a)) * 64 + lane]
        f32x4 t0a0 = acc00 + XC(0,0) + XC(1,0) + XC(2,0);   // z|r full sum
        f32x4 t0a1 = acc01 + XC(0,1) + XC(1,1) + XC(2,1);
        f32x4 nx0  = acc10 + XC(0,2);                       // gx_n
        f32x4 nx1  = acc11 + XC(0,3);
        f32x4 nh0  = XC(1,2) + XC(2,2);                     // gh_n (kept separate)
        f32x4 nh1  = XC(1,3) + XC(2,3);

        const int j = j0 + (row & 7);
        const float bz = bias[j], br = bias[1024 + j], bn = bias[2048 + j];
        _Float16* hw = hb + ((long)((s + 1) & 1) << 17);
        #pragma unroll
        for (int mi = 0; mi < 2; ++mi) {
            f32x4 t0 = mi ? t0a1 : t0a0;
            f32x4 nx = mi ? nx1 : nx0;
            f32x4 nh = mi ? nh1 : nh0;
            #pragma unroll
            for (int i = 0; i < 4; ++i) {
                float vr = __shfl(t0[i], lane + 8);          // r-pre from col row+8
                if (row < 8) {
                    int b = mgbase + mt2 * 32 + mi * 16 + (kg << 2) + i;
                    float z = 1.f / (1.f + __expf(-(t0[i] + bz)));
                    float r = 1.f / (1.f + __expf(-(vr + br)));
                    float inner = nx[i] + bn + nh[i] + r * (nh[i] + bn);
                    float e2 = __expf(2.f * inner);
                    float n = 1.f - 2.f / (e2 + 1.f);        // tanh(inner)
                    long o = ((long)b << 10) + j;
                    float hp = hf[o];
                    float hv = (1.f - z) * n + z * hp;
                    hf[o] = hv;
                    hw[o] = (_Float16)hv;
                    out[((long)b << 19) + ((long)s << 10) + j] = hv;
                }
            }
        }
    }
}

extern "C" void kernel_launch(void* const* d_in, const int* in_sizes, int n_in,
                              void* d_out, int out_size, void* d_ws, size_t ws_size,
                              hipStream_t stream)
{
    const float* x    = (const float*)d_in[0];
    const float* Wih  = (const float*)d_in[1];
    const float* Whh  = (const float*)d_in[2];
    const float* bias = (const float*)d_in[3];
    const float* h0   = (const float*)d_in[4];
    float* out = (float*)d_out;

    _Float16* ws16 = (_Float16*)d_ws;
    _Float16* pw = ws16 + O_PW;
    _Float16* xh = ws16 + O_X;
    _Float16* hb = ws16 + O_HB;
    float*    hf = (float*)(ws16 + O_HF);

    (void)hipFuncSetAttribute((const void*)gru_step,
                              hipFuncAttributeMaxDynamicSharedMemorySize, LDS_BYTES);

    prep_w<<<24576, 256, 0, stream>>>(Wih, Whh, pw);
    prep_x<<<32768, 256, 0, stream>>>(x, xh);
    prep_h<<<512, 256, 0, stream>>>(h0, hb, hf, out + 67108864L);

    for (int s = 0; s < 512; ++s) {
        gru_step<<<256, 512, LDS_BYTES, stream>>>(xh, pw, hb, hf, bias, out, s);
    }
}